// Round 10
// baseline (248.922 us; speedup 1.0000x reference)
//
#include <hip/hip_runtime.h>
#include <hip/hip_bf16.h>

// 2-layer GCN: out = A_hat @ relu((A_hat@X)@W1 + b1) @ W2 + b2,  A_hat = D^-1/2 (A+I) D^-1/2
// R15 (237.5us, best): split straight-line GEMMs (~33us pair). R16 FAILED: agg tail
//   removal -> aggs are LATENCY-bound, clamped duplicate loads are L1-free. R17 FAILED
//   (+4.5us): split-column gemms -> extra prologues/A-re-reads beat the staging saving;
//   gemms are near floor, reverted to R15 verbatim.
// R18: agg MLP deepening. 4 slots x 8-deep clamped batch (e += 32): exposed-latency
//   rounds/node E[ceil(deg/32)] ~= 1.07 vs 1.56 at 4-deep. Duplicates are L1-free
//   (R16-proven); +32 VGPR for in-flight loads is affordable at 256 threads.

static constexpr int N_NODES = 50000;
static constexpr int N_EDGES = 800000;
static constexpr int F_IN = 128;
static constexpr int HID  = 256;
static constexpr int F_OUT = 128;
static constexpr int NREP = 16;    // weight replicas (L2 spread for staging reads)

typedef __attribute__((ext_vector_type(8))) short short8;   // 8 bf16 raw bits (4 VGPRs)
typedef __attribute__((ext_vector_type(4))) float f32x4;

__device__ __forceinline__ unsigned short f2bf(float f) {   // RNE fp32->bf16
    union { float f; unsigned u; } x; x.f = f;
    unsigned r = x.u + 0x7FFF + ((x.u >> 16) & 1);
    return (unsigned short)(r >> 16);
}
__device__ __forceinline__ float bf2f(unsigned short h) {
    union { unsigned u; float f; } x; x.u = ((unsigned)h) << 16;
    return x.f;
}

// Fused independent prep: deg/pos atomics  |  W1^T x16  |  W2^T x16   (grid-partitioned)
__global__ void deg_wt_kernel(const int* __restrict__ dst, int* __restrict__ deg,
                              int* __restrict__ pos, int E,
                              const float* __restrict__ W1, unsigned short* __restrict__ w1t,
                              const float* __restrict__ W2, unsigned short* __restrict__ w2t,
                              int EB, int NB1) {
    const int b = blockIdx.x;
    if (b < EB) {
        int i = b * 256 + threadIdx.x;
        if (i < E) pos[i] = atomicAdd(&deg[dst[i]], 1);
    } else if (b < EB + NB1) {
        int t = (b - EB) * 256 + threadIdx.x;       // W1: F_IN rows x HID cols -> w1t[HID][F_IN]
        if (t < F_IN * HID) {
            int n = t / F_IN, k = t - n * F_IN;
            unsigned short v = f2bf(W1[(size_t)k * HID + n]);
#pragma unroll
            for (int r = 0; r < NREP; r++) w1t[(size_t)r * F_IN * HID + t] = v;
        }
    } else {
        int t = (b - EB - NB1) * 256 + threadIdx.x; // W2: HID rows x F_OUT cols -> w2t[F_OUT][HID]
        if (t < HID * F_OUT) {
            int n = t / HID, k = t - n * HID;
            unsigned short v = f2bf(W2[(size_t)k * F_OUT + n]);
#pragma unroll
            for (int r = 0; r < NREP; r++) w2t[(size_t)r * HID * F_OUT + t] = v;
        }
    }
}

// Fused: per-block sum of deg -> bsums, plus dinv[i] = rsqrt(deg+1).
__global__ __launch_bounds__(256) void scan_reduce_dinv(const int* __restrict__ deg,
                                                        int* __restrict__ bsums,
                                                        float* __restrict__ dinv, int N) {
    int i = blockIdx.x * 256 + threadIdx.x;
    int v = (i < N) ? deg[i] : 0;
    if (i < N) dinv[i] = rsqrtf((float)(v + 1));   // +1 = self loop
#pragma unroll
    for (int ofs = 32; ofs > 0; ofs >>= 1) v += __shfl_down(v, ofs);
    __shared__ int ws[4];
    if ((threadIdx.x & 63) == 0) ws[threadIdx.x >> 6] = v;
    __syncthreads();
    if (threadIdx.x == 0) bsums[blockIdx.x] = ws[0] + ws[1] + ws[2] + ws[3];
}

// Fused: blocks [0,nb): redundant LDS scan of bsums + intra-block scan of deg -> off;
// blocks [nb, ...): xs = bf16(dinv * x)  (dinv ready since scan_reduce_dinv).
__global__ __launch_bounds__(256) void scan_final_scalex(const int* __restrict__ deg,
                                                         const int* __restrict__ bsums,
                                                         int* __restrict__ off, int N, int nb,
                                                         const float* __restrict__ x,
                                                         const float* __restrict__ dinv,
                                                         unsigned short* __restrict__ xs) {
    const int tid = threadIdx.x;
    if ((int)blockIdx.x >= nb) {   // scalex partition
        int i = (blockIdx.x - nb) * 256 + tid;     // one thread per 8 elems
        if (i < N_NODES * F_IN / 8) {
            float dv = dinv[i >> 4];
            float4 v0 = ((const float4*)x)[i * 2];
            float4 v1 = ((const float4*)x)[i * 2 + 1];
            short8 o;
            o[0] = (short)f2bf(v0.x * dv); o[1] = (short)f2bf(v0.y * dv);
            o[2] = (short)f2bf(v0.z * dv); o[3] = (short)f2bf(v0.w * dv);
            o[4] = (short)f2bf(v1.x * dv); o[5] = (short)f2bf(v1.y * dv);
            o[6] = (short)f2bf(v1.z * dv); o[7] = (short)f2bf(v1.w * dv);
            *(short8*)(xs + (size_t)i * 8) = o;
        }
        return;
    }
    __shared__ int bs[256];
    __shared__ int s[256];
    bs[tid] = (tid < nb) ? bsums[tid] : 0;
    const int i = blockIdx.x * 256 + tid;
    int v = (i < N) ? deg[i] : 0;
    s[tid] = v;
    __syncthreads();
    for (int ofs = 1; ofs < 256; ofs <<= 1) {
        int tb = (tid >= ofs) ? bs[tid - ofs] : 0;
        int tv = (tid >= ofs) ? s[tid - ofs] : 0;
        __syncthreads();
        bs[tid] += tb;
        s[tid] += tv;
        __syncthreads();
    }
    int bbase = (blockIdx.x == 0) ? 0 : bs[blockIdx.x - 1];
    int excl = (tid == 0) ? 0 : s[tid - 1];
    if (i <= N) off[i] = bbase + excl;
}

// Pure scatter: csr[off[dst] + pos] = src.  No atomics.
__global__ void scatter_kernel(const int* __restrict__ src, const int* __restrict__ dst,
                               const int* __restrict__ pos, const int* __restrict__ off,
                               int* __restrict__ csr, int E) {
    int i = blockIdx.x * blockDim.x + threadIdx.x;
    if (i < E) csr[off[dst[i]] + pos[i]] = src[i];
}

// Wave-per-node aggregation over 128-dim bf16 rows, fp32 accumulate.
// Wave = 4 edge-slots x 16 lanes; 4 nodes per 256-block. 8-deep clamped predicated
// batch per slot (32 loads in flight per wave): E[latency rounds] 1.56 -> 1.07.
// Clamped duplicates hit the same L1 line (R16-proven free).
// MODE 0: out_bf16[n] = bf16( dinv[n] * (self + sum) )
// MODE 1: out_f32[n]  = dinv[n] * (self + sum) + bias
template <int MODE>
__global__ __launch_bounds__(256) void agg_bf16(const unsigned short* __restrict__ hs,
                                                const int* __restrict__ off,
                                                const int* __restrict__ csr,
                                                const float* __restrict__ dinv,
                                                const float* __restrict__ bias,
                                                void* __restrict__ outp, int N) {
    const int wid = threadIdx.x >> 6;
    const int n = blockIdx.x * 4 + wid;
    if (n >= N) return;
    const int lane = threadIdx.x & 63;
    const int lane16 = lane & 15;
    const int slot = lane >> 4;   // 0..3

    float va[8], vb[8], vc[8], vd[8];
#pragma unroll
    for (int j = 0; j < 8; j++) { va[j] = 0.f; vb[j] = 0.f; vc[j] = 0.f; vd[j] = 0.f; }

    if (slot == 0) {  // self loop
        short8 s = *(const short8*)(hs + (size_t)n * 128 + lane16 * 8);
#pragma unroll
        for (int j = 0; j < 8; j++) va[j] = bf2f((unsigned short)s[j]);
    }

    const int e0 = off[n];
    const int e1 = off[n + 1];
    for (int e = e0 + slot; e < e1; e += 32) {
        const int i1 = e + 4,  i2 = e + 8,  i3 = e + 12;
        const int i4 = e + 16, i5 = e + 20, i6 = e + 24, i7 = e + 28;
        const float f1 = (i1 < e1) ? 1.f : 0.f;
        const float f2 = (i2 < e1) ? 1.f : 0.f;
        const float f3 = (i3 < e1) ? 1.f : 0.f;
        const float f4 = (i4 < e1) ? 1.f : 0.f;
        const float f5 = (i5 < e1) ? 1.f : 0.f;
        const float f6 = (i6 < e1) ? 1.f : 0.f;
        const float f7 = (i7 < e1) ? 1.f : 0.f;
        const int c1 = min(i1, e1 - 1), c2 = min(i2, e1 - 1), c3 = min(i3, e1 - 1);
        const int c4 = min(i4, e1 - 1), c5 = min(i5, e1 - 1), c6 = min(i6, e1 - 1);
        const int c7 = min(i7, e1 - 1);
        int s0 = csr[e];
        int s1 = csr[c1];
        int s2 = csr[c2];
        int s3 = csr[c3];
        int s4 = csr[c4];
        int s5 = csr[c5];
        int s6 = csr[c6];
        int s7 = csr[c7];
        short8 v0 = *(const short8*)(hs + (size_t)s0 * 128 + lane16 * 8);
        short8 v1 = *(const short8*)(hs + (size_t)s1 * 128 + lane16 * 8);
        short8 v2 = *(const short8*)(hs + (size_t)s2 * 128 + lane16 * 8);
        short8 v3 = *(const short8*)(hs + (size_t)s3 * 128 + lane16 * 8);
        short8 v4 = *(const short8*)(hs + (size_t)s4 * 128 + lane16 * 8);
        short8 v5 = *(const short8*)(hs + (size_t)s5 * 128 + lane16 * 8);
        short8 v6 = *(const short8*)(hs + (size_t)s6 * 128 + lane16 * 8);
        short8 v7 = *(const short8*)(hs + (size_t)s7 * 128 + lane16 * 8);
#pragma unroll
        for (int j = 0; j < 8; j++) va[j] += bf2f((unsigned short)v0[j]);
#pragma unroll
        for (int j = 0; j < 8; j++) vb[j] = fmaf(f1, bf2f((unsigned short)v1[j]), vb[j]);
#pragma unroll
        for (int j = 0; j < 8; j++) vc[j] = fmaf(f2, bf2f((unsigned short)v2[j]), vc[j]);
#pragma unroll
        for (int j = 0; j < 8; j++) vd[j] = fmaf(f3, bf2f((unsigned short)v3[j]), vd[j]);
#pragma unroll
        for (int j = 0; j < 8; j++) va[j] = fmaf(f4, bf2f((unsigned short)v4[j]), va[j]);
#pragma unroll
        for (int j = 0; j < 8; j++) vb[j] = fmaf(f5, bf2f((unsigned short)v5[j]), vb[j]);
#pragma unroll
        for (int j = 0; j < 8; j++) vc[j] = fmaf(f6, bf2f((unsigned short)v6[j]), vc[j]);
#pragma unroll
        for (int j = 0; j < 8; j++) vd[j] = fmaf(f7, bf2f((unsigned short)v7[j]), vd[j]);
    }
#pragma unroll
    for (int j = 0; j < 8; j++) va[j] += vb[j] + vc[j] + vd[j];

#pragma unroll
    for (int j = 0; j < 8; j++) va[j] += __shfl_down(va[j], 32);
#pragma unroll
    for (int j = 0; j < 8; j++) va[j] += __shfl_down(va[j], 16);

    if (lane < 16) {
        float dv = dinv[n];
        if (MODE == 0) {
            short8 o;
#pragma unroll
            for (int j = 0; j < 8; j++) o[j] = (short)f2bf(va[j] * dv);
            *(short8*)((unsigned short*)outp + (size_t)n * 128 + lane * 8) = o;
        } else {
            float* op = (float*)outp + (size_t)n * 128 + lane * 8;
            float4 o0, o1;
            o0.x = va[0] * dv + bias[lane * 8 + 0];
            o0.y = va[1] * dv + bias[lane * 8 + 1];
            o0.z = va[2] * dv + bias[lane * 8 + 2];
            o0.w = va[3] * dv + bias[lane * 8 + 3];
            o1.x = va[4] * dv + bias[lane * 8 + 4];
            o1.y = va[5] * dv + bias[lane * 8 + 5];
            o1.z = va[6] * dv + bias[lane * 8 + 6];
            o1.w = va[7] * dv + bias[lane * 8 + 7];
            ((float4*)op)[0] = o0;
            ((float4*)op)[1] = o1;
        }
    }
}

// GEMM1 (straight-line, R15 verbatim): h2[m, 0:256] = relu(Y[m, 0:128] @ W1 + b1).
// 391 blocks x 512 thr (8 waves); block tile = 128 rows; wave = 16 rows x 256 cols.
// W1 in fragment-order LDS (R13-verified mapping, 64 KB, 2 blocks/CU).
__global__ __launch_bounds__(512, 2) void gemm1(const unsigned short* __restrict__ Y,
                                                const unsigned short* __restrict__ w1t,
                                                const float* __restrict__ b1,
                                                unsigned short* __restrict__ h2, int M) {
    __shared__ unsigned short w1l[F_IN * HID];   // 65536 B, fragment-order

    const int tid = threadIdx.x;
    const int wid = tid >> 6;
    const int lane = tid & 63;
    const int an = lane & 15;
    const int q = lane >> 4;
    const int rep = blockIdx.x & (NREP - 1);

    {   // stage W1 replica -> fragment-order LDS (R13-verified)
        const unsigned short* w1r = w1t + (size_t)rep * F_IN * HID;
        for (int i = tid; i < 4096; i += 512) {
            const int cw = i >> 9;
            const int t  = (i >> 8) & 1;
            const int c  = (i >> 6) & 3;
            const int l  = i & 63;
            const int col = cw * 32 + t * 16 + (l & 15);
            const int off = col * F_IN + (l >> 4) * 8 + c * 32;
            *(short8*)(w1l + (size_t)i * 8) = *(const short8*)(w1r + off);
        }
    }
    float bvs[16];
#pragma unroll
    for (int t = 0; t < 16; t++) bvs[t] = b1[t * 16 + an];
    __syncthreads();

    const int m0 = blockIdx.x * 128 + wid * 16;
    int row = m0 + an;
    if (row >= M) row = M - 1;
    short8 a[4];
    {
        const unsigned short* yp = Y + (size_t)row * F_IN + q * 8;
#pragma unroll
        for (int c = 0; c < 4; c++) a[c] = *(const short8*)(yp + c * 32);
    }
    const int mb = m0 + q * 4;
#pragma unroll
    for (int tt = 0; tt < 16; tt++) {
        f32x4 acc = {0.f, 0.f, 0.f, 0.f};
#pragma unroll
        for (int c = 0; c < 4; c++) {
            const short8 b = *(const short8*)(w1l +
                              ((size_t)(((tt >> 1) * 8 + (tt & 1) * 4 + c) * 64 + lane)) * 8);
            acc = __builtin_amdgcn_mfma_f32_16x16x32_bf16(a[c], b, acc, 0, 0, 0);
        }
        const int col = tt * 16 + an;
#pragma unroll
        for (int rr = 0; rr < 4; rr++) {
            const int m = mb + rr;
            if (m < M) h2[(size_t)m * HID + col] = f2bf(fmaxf(acc[rr] + bvs[tt], 0.f));
        }
    }
}

// GEMM2 (straight-line, R15 verbatim): hs2[m, 0:128] = dinv[m] * (h2[m, 0:256] @ W2).
__global__ __launch_bounds__(512, 2) void gemm2(const unsigned short* __restrict__ h2,
                                                const unsigned short* __restrict__ w2t,
                                                const float* __restrict__ dinv,
                                                unsigned short* __restrict__ hs2, int M) {
    __shared__ unsigned short w2l[HID * F_OUT];   // 65536 B, fragment-order

    const int tid = threadIdx.x;
    const int wid = tid >> 6;
    const int lane = tid & 63;
    const int an = lane & 15;
    const int q = lane >> 4;
    const int rep = blockIdx.x & (NREP - 1);

    {   // stage W2 replica -> fragment-order LDS (R13-verified)
        const unsigned short* w2r = w2t + (size_t)rep * HID * F_OUT;
        for (int i = tid; i < 4096; i += 512) {
            const int cw = i >> 9;
            const int c  = (i >> 6) & 7;
            const int l  = i & 63;
            const int colB = cw * 16 + (l & 15);
            const int off = colB * HID + (l >> 4) * 8 + c * 32;
            *(short8*)(w2l + (size_t)i * 8) = *(const short8*)(w2r + off);
        }
    }
    __syncthreads();

    const int m0 = blockIdx.x * 128 + wid * 16;
    int row = m0 + an;
    if (row >= M) row = M - 1;
    short8 a[8];
    {
        const unsigned short* hp = h2 + (size_t)row * HID + q * 8;
#pragma unroll
        for (int c = 0; c < 8; c++) a[c] = *(const short8*)(hp + c * 32);
    }
    const int mb = m0 + q * 4;
    float dv[4];
#pragma unroll
    for (int rr = 0; rr < 4; rr++) dv[rr] = (mb + rr < M) ? dinv[mb + rr] : 0.f;
#pragma unroll
    for (int tt = 0; tt < 8; tt++) {
        f32x4 acc = {0.f, 0.f, 0.f, 0.f};
#pragma unroll
        for (int c = 0; c < 8; c++) {
            const short8 b = *(const short8*)(w2l + ((size_t)((tt * 8 + c) * 64 + lane)) * 8);
            acc = __builtin_amdgcn_mfma_f32_16x16x32_bf16(a[c], b, acc, 0, 0, 0);
        }
        const int col = tt * 16 + an;
#pragma unroll
        for (int rr = 0; rr < 4; rr++) {
            const int m = mb + rr;
            if (m < M) hs2[(size_t)m * F_OUT + col] = f2bf(acc[rr] * dv[rr]);
        }
    }
}

extern "C" void kernel_launch(void* const* d_in, const int* in_sizes, int n_in,
                              void* d_out, int out_size, void* d_ws, size_t ws_size,
                              hipStream_t stream) {
    const float* x  = (const float*)d_in[0];
    const int*   ei = (const int*)d_in[1];   // [2,E] int32
    const float* W1 = (const float*)d_in[2];
    const float* b1 = (const float*)d_in[3];
    const float* W2 = (const float*)d_in[4];
    const float* b2 = (const float*)d_in[5];

    const int N = N_NODES;
    const int E = N_EDGES;
    const int* srcp = ei;
    const int* dstp = ei + E;

    char* base = (char*)d_ws;
    size_t o = 0;
    auto alloc = [&](size_t bytes) {
        void* p = base + o;
        o = (o + bytes + 255) & ~(size_t)255;
        return p;
    };
    int*            deg  = (int*)alloc((size_t)N * 4);
    int*            offs = (int*)alloc((size_t)(N + 1) * 4);
    float*          dinv = (float*)alloc((size_t)N * 4);
    int*            bsum = (int*)alloc(256 * 4);
    int*            pos  = (int*)alloc((size_t)E * 4);
    int*            csr  = (int*)alloc((size_t)E * 4);
    unsigned short* xs   = (unsigned short*)alloc((size_t)N * F_IN * 2);  // dinv*x, bf16
    unsigned short* Y    = (unsigned short*)alloc((size_t)N * F_IN * 2);  // A_hat@X, bf16
    unsigned short* h2   = (unsigned short*)alloc((size_t)N * HID * 2);   // relu(Y@W1+b1), bf16
    unsigned short* w1t  = (unsigned short*)alloc((size_t)NREP * F_IN * HID * 2);
    unsigned short* w2t  = (unsigned short*)alloc((size_t)NREP * HID * F_OUT * 2);
    unsigned short* hs2  = xs;  // xs dead after agg1

    hipMemsetAsync(deg, 0, (size_t)N * 4, stream);

    const int NB  = (N + 256) / 256;           // 196, covers i==N in scan_final
    const int NBX = (N * F_IN / 8 + 255) / 256;
    const int EB  = (E + 255) / 256;
    const int NB1 = (F_IN * HID + 255) / 256;
    const int NB2 = (HID * F_OUT + 255) / 256;
    const int GB  = (N + 127) / 128;           // 391 GEMM blocks

    deg_wt_kernel<<<EB + NB1 + NB2, 256, 0, stream>>>(dstp, deg, pos, E, W1, w1t, W2, w2t, EB, NB1);
    scan_reduce_dinv<<<NB, 256, 0, stream>>>(deg, bsum, dinv, N);
    scan_final_scalex<<<NB + NBX, 256, 0, stream>>>(deg, bsum, offs, N, NB, x, dinv, xs);
    scatter_kernel<<<EB, 256, 0, stream>>>(srcp, dstp, pos, offs, csr, E);

    // layer 1 agg: Y = A_hat@X (bf16 gather, 8-deep clamped batches)
    agg_bf16<0><<<(N + 3) / 4, 256, 0, stream>>>(xs, offs, csr, dinv, nullptr, Y, N);
    // split GEMMs (R15 verbatim): h2 = relu(Y@W1+b1);  hs2 = dinv*(h2@W2)
    gemm1<<<GB, 512, 0, stream>>>(Y, w1t, b1, h2, N);
    gemm2<<<GB, 512, 0, stream>>>(h2, w2t, dinv, hs2, N);
    // layer 2 agg: out = dinv*(hs2[self]+gather) + b2
    agg_bf16<1><<<(N + 3) / 4, 256, 0, stream>>>(hs2, offs, csr, dinv, b2, d_out, N);
}

// Round 12
// 235.750 us; speedup vs baseline: 1.0559x; 1.0559x over previous
//
#include <hip/hip_runtime.h>
#include <hip/hip_bf16.h>

// 2-layer GCN: out = A_hat @ relu((A_hat@X)@W1 + b1) @ W2 + b2,  A_hat = D^-1/2 (A+I) D^-1/2
// R15 (237.5us, best): split straight-line GEMMs (~33us pair), 4-deep clamped aggs.
// R16 FAILED: bulk+tail agg -> aggs latency-sensitive, clamped dups are L1-free.
// R17 FAILED: split-column gemms -> gemms at floor, R15 verbatim kept.
// R18 FAILED (+agg data!): 8-deep clamps -> agg_bf16 = 43.6us, VALUBusy 49%, HBM 31%:
//   aggs are VALU-ISSUE-bound; extra clamp/predicate/duplicate-fma VALU hurt.
// R19 (resubmit; R11 bench was an infra failure -- container acquire, no kernel signal):
//   revert to 4-deep + cut VALU per row. (a) CSR PADDING: each node's region padded
//   to multiple of 16 with entries pointing at a zero row (row N, zeroed once) -> inner
//   loop has ZERO predicates/clamps (saves ~12 VALU/batch/lane); padding adds exact 0.
//   (b) csr stores BYTE offsets (src<<8); lane's 16B sub-offset folded into base ptr.

static constexpr int N_NODES = 50000;
static constexpr int N_EDGES = 800000;
static constexpr int F_IN = 128;
static constexpr int HID  = 256;
static constexpr int F_OUT = 128;
static constexpr int NREP = 16;    // weight replicas (L2 spread for staging reads)

typedef __attribute__((ext_vector_type(8))) short short8;   // 8 bf16 raw bits (4 VGPRs)
typedef __attribute__((ext_vector_type(4))) float f32x4;

__device__ __forceinline__ unsigned short f2bf(float f) {   // RNE fp32->bf16
    union { float f; unsigned u; } x; x.f = f;
    unsigned r = x.u + 0x7FFF + ((x.u >> 16) & 1);
    return (unsigned short)(r >> 16);
}
__device__ __forceinline__ float bf2f(unsigned short h) {
    union { unsigned u; float f; } x; x.u = ((unsigned)h) << 16;
    return x.f;
}

// Fused independent prep: deg/pos atomics  |  W1^T x16  |  W2^T x16   (grid-partitioned)
__global__ void deg_wt_kernel(const int* __restrict__ dst, int* __restrict__ deg,
                              int* __restrict__ pos, int E,
                              const float* __restrict__ W1, unsigned short* __restrict__ w1t,
                              const float* __restrict__ W2, unsigned short* __restrict__ w2t,
                              int EB, int NB1) {
    const int b = blockIdx.x;
    if (b < EB) {
        int i = b * 256 + threadIdx.x;
        if (i < E) pos[i] = atomicAdd(&deg[dst[i]], 1);
    } else if (b < EB + NB1) {
        int t = (b - EB) * 256 + threadIdx.x;       // W1: F_IN rows x HID cols -> w1t[HID][F_IN]
        if (t < F_IN * HID) {
            int n = t / F_IN, k = t - n * F_IN;
            unsigned short v = f2bf(W1[(size_t)k * HID + n]);
#pragma unroll
            for (int r = 0; r < NREP; r++) w1t[(size_t)r * F_IN * HID + t] = v;
        }
    } else {
        int t = (b - EB - NB1) * 256 + threadIdx.x; // W2: HID rows x F_OUT cols -> w2t[F_OUT][HID]
        if (t < HID * F_OUT) {
            int n = t / HID, k = t - n * HID;
            unsigned short v = f2bf(W2[(size_t)k * F_OUT + n]);
#pragma unroll
            for (int r = 0; r < NREP; r++) w2t[(size_t)r * HID * F_OUT + t] = v;
        }
    }
}

// Fused: per-block sum of PADDED deg -> bsums, plus dinv[i] = rsqrt(deg+1) (true deg).
__global__ __launch_bounds__(256) void scan_reduce_dinv(const int* __restrict__ deg,
                                                        int* __restrict__ bsums,
                                                        float* __restrict__ dinv, int N) {
    int i = blockIdx.x * 256 + threadIdx.x;
    int d = (i < N) ? deg[i] : 0;
    if (i < N) dinv[i] = rsqrtf((float)(d + 1));   // +1 = self loop
    int v = (i < N) ? ((d + 15) & ~15) : 0;        // padded degree
#pragma unroll
    for (int ofs = 32; ofs > 0; ofs >>= 1) v += __shfl_down(v, ofs);
    __shared__ int ws[4];
    if ((threadIdx.x & 63) == 0) ws[threadIdx.x >> 6] = v;
    __syncthreads();
    if (threadIdx.x == 0) bsums[blockIdx.x] = ws[0] + ws[1] + ws[2] + ws[3];
}

// Fused: blocks [0,nb): redundant LDS scan of bsums + intra-block scan of PADDED deg
// -> off; blocks [nb, ...): xs = bf16(dinv * x).
__global__ __launch_bounds__(256) void scan_final_scalex(const int* __restrict__ deg,
                                                         const int* __restrict__ bsums,
                                                         int* __restrict__ off, int N, int nb,
                                                         const float* __restrict__ x,
                                                         const float* __restrict__ dinv,
                                                         unsigned short* __restrict__ xs) {
    const int tid = threadIdx.x;
    if ((int)blockIdx.x >= nb) {   // scalex partition
        int i = (blockIdx.x - nb) * 256 + tid;     // one thread per 8 elems
        if (i < N_NODES * F_IN / 8) {
            float dv = dinv[i >> 4];
            float4 v0 = ((const float4*)x)[i * 2];
            float4 v1 = ((const float4*)x)[i * 2 + 1];
            short8 o;
            o[0] = (short)f2bf(v0.x * dv); o[1] = (short)f2bf(v0.y * dv);
            o[2] = (short)f2bf(v0.z * dv); o[3] = (short)f2bf(v0.w * dv);
            o[4] = (short)f2bf(v1.x * dv); o[5] = (short)f2bf(v1.y * dv);
            o[6] = (short)f2bf(v1.z * dv); o[7] = (short)f2bf(v1.w * dv);
            *(short8*)(xs + (size_t)i * 8) = o;
        }
        return;
    }
    __shared__ int bs[256];
    __shared__ int s[256];
    bs[tid] = (tid < nb) ? bsums[tid] : 0;
    const int i = blockIdx.x * 256 + tid;
    int v = (i < N) ? ((deg[i] + 15) & ~15) : 0;   // padded degree
    s[tid] = v;
    __syncthreads();
    for (int ofs = 1; ofs < 256; ofs <<= 1) {
        int tb = (tid >= ofs) ? bs[tid - ofs] : 0;
        int tv = (tid >= ofs) ? s[tid - ofs] : 0;
        __syncthreads();
        bs[tid] += tb;
        s[tid] += tv;
        __syncthreads();
    }
    int bbase = (blockIdx.x == 0) ? 0 : bs[blockIdx.x - 1];
    int excl = (tid == 0) ? 0 : s[tid - 1];
    if (i <= N) off[i] = bbase + excl;
}

// Scatter (byte offsets: src<<8) + pad-fill partition (zero-row offset N<<8).
__global__ void scatter_kernel(const int* __restrict__ src, const int* __restrict__ dst,
                               const int* __restrict__ pos, const int* __restrict__ off,
                               const int* __restrict__ deg, int* __restrict__ csr,
                               int E, int N, int EB) {
    const int b = blockIdx.x;
    if (b < EB) {
        int i = b * 256 + threadIdx.x;
        if (i < E) csr[off[dst[i]] + pos[i]] = src[i] << 8;
    } else {
        int n = (b - EB) * 256 + threadIdx.x;
        if (n < N) {
            const int zoff = N << 8;
            for (int e = off[n] + deg[n]; e < off[n + 1]; e++) csr[e] = zoff;
        }
    }
}

// Wave-per-node aggregation over 128-dim bf16 rows, fp32 accumulate.
// Wave = 4 edge-slots x 16 lanes; 4 nodes per 256-block. CSR padded to x16 with
// zero-row byte offsets -> NO predicates/clamps in the loop; csr holds byte offsets.
// MODE 0: out_bf16[n] = bf16( dinv[n] * (self + sum) )
// MODE 1: out_f32[n]  = dinv[n] * (self + sum) + bias
template <int MODE>
__global__ __launch_bounds__(256) void agg_bf16(const unsigned short* __restrict__ hs,
                                                const int* __restrict__ off,
                                                const int* __restrict__ csr,
                                                const float* __restrict__ dinv,
                                                const float* __restrict__ bias,
                                                void* __restrict__ outp, int N) {
    const int wid = threadIdx.x >> 6;
    const int n = blockIdx.x * 4 + wid;
    if (n >= N) return;
    const int lane = threadIdx.x & 63;
    const int lane16 = lane & 15;
    const int slot = lane >> 4;   // 0..3
    const char* hsl = (const char*)hs + lane16 * 16;   // lane's 16B sub-offset folded in

    float va[8], vb[8], vc[8], vd[8];
#pragma unroll
    for (int j = 0; j < 8; j++) { va[j] = 0.f; vb[j] = 0.f; vc[j] = 0.f; vd[j] = 0.f; }

    if (slot == 0) {  // self loop
        short8 s = *(const short8*)(hsl + ((size_t)n << 8));
#pragma unroll
        for (int j = 0; j < 8; j++) va[j] = bf2f((unsigned short)s[j]);
    }

    const int e0 = off[n];
    const int e1 = off[n + 1];   // padded end (multiple of 16 past e0)
    for (int e = e0 + slot; e < e1; e += 16) {
        int o0 = csr[e];
        int o1 = csr[e + 4];
        int o2 = csr[e + 8];
        int o3 = csr[e + 12];
        short8 v0 = *(const short8*)(hsl + (unsigned)o0);
        short8 v1 = *(const short8*)(hsl + (unsigned)o1);
        short8 v2 = *(const short8*)(hsl + (unsigned)o2);
        short8 v3 = *(const short8*)(hsl + (unsigned)o3);
#pragma unroll
        for (int j = 0; j < 8; j++) va[j] += bf2f((unsigned short)v0[j]);
#pragma unroll
        for (int j = 0; j < 8; j++) vb[j] += bf2f((unsigned short)v1[j]);
#pragma unroll
        for (int j = 0; j < 8; j++) vc[j] += bf2f((unsigned short)v2[j]);
#pragma unroll
        for (int j = 0; j < 8; j++) vd[j] += bf2f((unsigned short)v3[j]);
    }
#pragma unroll
    for (int j = 0; j < 8; j++) va[j] += vb[j] + vc[j] + vd[j];

#pragma unroll
    for (int j = 0; j < 8; j++) va[j] += __shfl_down(va[j], 32);
#pragma unroll
    for (int j = 0; j < 8; j++) va[j] += __shfl_down(va[j], 16);

    if (lane < 16) {
        float dv = dinv[n];
        if (MODE == 0) {
            short8 o;
#pragma unroll
            for (int j = 0; j < 8; j++) o[j] = (short)f2bf(va[j] * dv);
            *(short8*)((unsigned short*)outp + (size_t)n * 128 + lane * 8) = o;
        } else {
            float* op = (float*)outp + (size_t)n * 128 + lane * 8;
            float4 o0, o1;
            o0.x = va[0] * dv + bias[lane * 8 + 0];
            o0.y = va[1] * dv + bias[lane * 8 + 1];
            o0.z = va[2] * dv + bias[lane * 8 + 2];
            o0.w = va[3] * dv + bias[lane * 8 + 3];
            o1.x = va[4] * dv + bias[lane * 8 + 4];
            o1.y = va[5] * dv + bias[lane * 8 + 5];
            o1.z = va[6] * dv + bias[lane * 8 + 6];
            o1.w = va[7] * dv + bias[lane * 8 + 7];
            ((float4*)op)[0] = o0;
            ((float4*)op)[1] = o1;
        }
    }
}

// GEMM1 (straight-line, R15 verbatim): h2[m, 0:256] = relu(Y[m, 0:128] @ W1 + b1).
// 391 blocks x 512 thr (8 waves); block tile = 128 rows; wave = 16 rows x 256 cols.
// W1 in fragment-order LDS (R13-verified mapping, 64 KB, 2 blocks/CU).
__global__ __launch_bounds__(512, 2) void gemm1(const unsigned short* __restrict__ Y,
                                                const unsigned short* __restrict__ w1t,
                                                const float* __restrict__ b1,
                                                unsigned short* __restrict__ h2, int M) {
    __shared__ unsigned short w1l[F_IN * HID];   // 65536 B, fragment-order

    const int tid = threadIdx.x;
    const int wid = tid >> 6;
    const int lane = tid & 63;
    const int an = lane & 15;
    const int q = lane >> 4;
    const int rep = blockIdx.x & (NREP - 1);

    {   // stage W1 replica -> fragment-order LDS (R13-verified)
        const unsigned short* w1r = w1t + (size_t)rep * F_IN * HID;
        for (int i = tid; i < 4096; i += 512) {
            const int cw = i >> 9;
            const int t  = (i >> 8) & 1;
            const int c  = (i >> 6) & 3;
            const int l  = i & 63;
            const int col = cw * 32 + t * 16 + (l & 15);
            const int off = col * F_IN + (l >> 4) * 8 + c * 32;
            *(short8*)(w1l + (size_t)i * 8) = *(const short8*)(w1r + off);
        }
    }
    float bvs[16];
#pragma unroll
    for (int t = 0; t < 16; t++) bvs[t] = b1[t * 16 + an];
    __syncthreads();

    const int m0 = blockIdx.x * 128 + wid * 16;
    int row = m0 + an;
    if (row >= M) row = M - 1;
    short8 a[4];
    {
        const unsigned short* yp = Y + (size_t)row * F_IN + q * 8;
#pragma unroll
        for (int c = 0; c < 4; c++) a[c] = *(const short8*)(yp + c * 32);
    }
    const int mb = m0 + q * 4;
#pragma unroll
    for (int tt = 0; tt < 16; tt++) {
        f32x4 acc = {0.f, 0.f, 0.f, 0.f};
#pragma unroll
        for (int c = 0; c < 4; c++) {
            const short8 b = *(const short8*)(w1l +
                              ((size_t)(((tt >> 1) * 8 + (tt & 1) * 4 + c) * 64 + lane)) * 8);
            acc = __builtin_amdgcn_mfma_f32_16x16x32_bf16(a[c], b, acc, 0, 0, 0);
        }
        const int col = tt * 16 + an;
#pragma unroll
        for (int rr = 0; rr < 4; rr++) {
            const int m = mb + rr;
            if (m < M) h2[(size_t)m * HID + col] = f2bf(fmaxf(acc[rr] + bvs[tt], 0.f));
        }
    }
}

// GEMM2 (straight-line, R15 verbatim): hs2[m, 0:128] = dinv[m] * (h2[m, 0:256] @ W2).
__global__ __launch_bounds__(512, 2) void gemm2(const unsigned short* __restrict__ h2,
                                                const unsigned short* __restrict__ w2t,
                                                const float* __restrict__ dinv,
                                                unsigned short* __restrict__ hs2, int M) {
    __shared__ unsigned short w2l[HID * F_OUT];   // 65536 B, fragment-order

    const int tid = threadIdx.x;
    const int wid = tid >> 6;
    const int lane = tid & 63;
    const int an = lane & 15;
    const int q = lane >> 4;
    const int rep = blockIdx.x & (NREP - 1);

    {   // stage W2 replica -> fragment-order LDS (R13-verified)
        const unsigned short* w2r = w2t + (size_t)rep * HID * F_OUT;
        for (int i = tid; i < 4096; i += 512) {
            const int cw = i >> 9;
            const int c  = (i >> 6) & 7;
            const int l  = i & 63;
            const int colB = cw * 16 + (l & 15);
            const int off = colB * HID + (l >> 4) * 8 + c * 32;
            *(short8*)(w2l + (size_t)i * 8) = *(const short8*)(w2r + off);
        }
    }
    __syncthreads();

    const int m0 = blockIdx.x * 128 + wid * 16;
    int row = m0 + an;
    if (row >= M) row = M - 1;
    short8 a[8];
    {
        const unsigned short* hp = h2 + (size_t)row * HID + q * 8;
#pragma unroll
        for (int c = 0; c < 8; c++) a[c] = *(const short8*)(hp + c * 32);
    }
    const int mb = m0 + q * 4;
    float dv[4];
#pragma unroll
    for (int rr = 0; rr < 4; rr++) dv[rr] = (mb + rr < M) ? dinv[mb + rr] : 0.f;
#pragma unroll
    for (int tt = 0; tt < 8; tt++) {
        f32x4 acc = {0.f, 0.f, 0.f, 0.f};
#pragma unroll
        for (int c = 0; c < 8; c++) {
            const short8 b = *(const short8*)(w2l + ((size_t)((tt * 8 + c) * 64 + lane)) * 8);
            acc = __builtin_amdgcn_mfma_f32_16x16x32_bf16(a[c], b, acc, 0, 0, 0);
        }
        const int col = tt * 16 + an;
#pragma unroll
        for (int rr = 0; rr < 4; rr++) {
            const int m = mb + rr;
            if (m < M) hs2[(size_t)m * F_OUT + col] = f2bf(acc[rr] * dv[rr]);
        }
    }
}

extern "C" void kernel_launch(void* const* d_in, const int* in_sizes, int n_in,
                              void* d_out, int out_size, void* d_ws, size_t ws_size,
                              hipStream_t stream) {
    const float* x  = (const float*)d_in[0];
    const int*   ei = (const int*)d_in[1];   // [2,E] int32
    const float* W1 = (const float*)d_in[2];
    const float* b1 = (const float*)d_in[3];
    const float* W2 = (const float*)d_in[4];
    const float* b2 = (const float*)d_in[5];

    const int N = N_NODES;
    const int E = N_EDGES;
    const int* srcp = ei;
    const int* dstp = ei + E;

    char* base = (char*)d_ws;
    size_t o = 0;
    auto alloc = [&](size_t bytes) {
        void* p = base + o;
        o = (o + bytes + 255) & ~(size_t)255;
        return p;
    };
    int*            deg  = (int*)alloc((size_t)N * 4);
    int*            offs = (int*)alloc((size_t)(N + 1) * 4);
    float*          dinv = (float*)alloc((size_t)N * 4);
    int*            bsum = (int*)alloc(256 * 4);
    int*            pos  = (int*)alloc((size_t)E * 4);
    int*            csr  = (int*)alloc(((size_t)E + 16 * (N + 1)) * 4);   // padded CSR
    unsigned short* xs   = (unsigned short*)alloc((size_t)(N + 1) * F_IN * 2); // +zero row N
    unsigned short* Y    = (unsigned short*)alloc((size_t)N * F_IN * 2);  // A_hat@X, bf16
    unsigned short* h2   = (unsigned short*)alloc((size_t)N * HID * 2);   // relu(Y@W1+b1), bf16
    unsigned short* w1t  = (unsigned short*)alloc((size_t)NREP * F_IN * HID * 2);
    unsigned short* w2t  = (unsigned short*)alloc((size_t)NREP * HID * F_OUT * 2);
    unsigned short* hs2  = xs;  // xs dead after agg1 (row N stays zero for agg2)

    hipMemsetAsync(deg, 0, (size_t)N * 4, stream);
    hipMemsetAsync(xs + (size_t)N * F_IN, 0, F_IN * 2, stream);   // zero row N

    const int NB  = (N + 256) / 256;           // 196, covers i==N in scan_final
    const int NBX = (N * F_IN / 8 + 255) / 256;
    const int NBn = (N + 255) / 256;
    const int EB  = (E + 255) / 256;
    const int NB1 = (F_IN * HID + 255) / 256;
    const int NB2 = (HID * F_OUT + 255) / 256;
    const int GB  = (N + 127) / 128;           // 391 GEMM blocks

    deg_wt_kernel<<<EB + NB1 + NB2, 256, 0, stream>>>(dstp, deg, pos, E, W1, w1t, W2, w2t, EB, NB1);
    scan_reduce_dinv<<<NB, 256, 0, stream>>>(deg, bsum, dinv, N);
    scan_final_scalex<<<NB + NBX, 256, 0, stream>>>(deg, bsum, offs, N, NB, x, dinv, xs);
    scatter_kernel<<<EB + NBn, 256, 0, stream>>>(srcp, dstp, pos, offs, deg, csr, E, N, EB);

    // layer 1 agg: Y = A_hat@X (bf16 gather, padded predicate-free batches)
    agg_bf16<0><<<(N + 3) / 4, 256, 0, stream>>>(xs, offs, csr, dinv, nullptr, Y, N);
    // split GEMMs (R15 verbatim): h2 = relu(Y@W1+b1);  hs2 = dinv*(h2@W2)
    gemm1<<<GB, 512, 0, stream>>>(Y, w1t, b1, h2, N);
    gemm2<<<GB, 512, 0, stream>>>(h2, w2t, dinv, hs2, N);
    // layer 2 agg: out = dinv*(hs2[self]+gather) + b2
    agg_bf16<1><<<(N + 3) / 4, 256, 0, stream>>>(hs2, offs, csr, dinv, b2, d_out, N);
}

// Round 13
// 234.534 us; speedup vs baseline: 1.0613x; 1.0052x over previous
//
#include <hip/hip_runtime.h>
#include <hip/hip_bf16.h>

// 2-layer GCN: out = A_hat @ relu((A_hat@X)@W1 + b1) @ W2 + b2,  A_hat = D^-1/2 (A+I) D^-1/2
// R15 (237.5): split straight-line GEMMs (~33us pair). R16/R17 FAILED (agg tail, split-col).
// R18 FAILED but measured aggs: 43.6us each, VALUBusy 49% / HBM 31% -> VALU-issue-bound.
// R19 (235.75, best): CSR padded to x16 w/ zero-row byte offsets -> predicate-free agg
//   inner loop; aggs ~37us each. Aggs still the largest controllable block (~74us).
// R20: packed-fp32 agg arithmetic. Accumulators as float2 pairs; each loaded dword
//   unpacks to 2 exact f32 (d<<16, d&0xFFFF0000) + ONE v_pk_add_f32 (CDNA VOP3P):
//   ~3 VALU / 2 elems vs ~6. Memory shape untouched; per-channel chains bit-identical
//   to R19. Epilogue expands pairs to va[8], proven shuffle-reduce verbatim.

static constexpr int N_NODES = 50000;
static constexpr int N_EDGES = 800000;
static constexpr int F_IN = 128;
static constexpr int HID  = 256;
static constexpr int F_OUT = 128;
static constexpr int NREP = 16;    // weight replicas (L2 spread for staging reads)

typedef __attribute__((ext_vector_type(8))) short short8;   // 8 bf16 raw bits (4 VGPRs)
typedef __attribute__((ext_vector_type(4))) float f32x4;
typedef __attribute__((ext_vector_type(2))) float f32x2;
typedef __attribute__((ext_vector_type(4))) int   i32x4;

__device__ __forceinline__ unsigned short f2bf(float f) {   // RNE fp32->bf16
    union { float f; unsigned u; } x; x.f = f;
    unsigned r = x.u + 0x7FFF + ((x.u >> 16) & 1);
    return (unsigned short)(r >> 16);
}
__device__ __forceinline__ float bf2f(unsigned short h) {
    union { unsigned u; float f; } x; x.u = ((unsigned)h) << 16;
    return x.f;
}
__device__ __forceinline__ f32x2 unpk(int d) {   // dword [bf16_lo | bf16_hi] -> 2 exact f32
    union { unsigned u; float f; } lo, hi;
    lo.u = (unsigned)d << 16;
    hi.u = (unsigned)d & 0xFFFF0000u;
    return (f32x2){lo.f, hi.f};
}

// Fused independent prep: deg/pos atomics  |  W1^T x16  |  W2^T x16   (grid-partitioned)
__global__ void deg_wt_kernel(const int* __restrict__ dst, int* __restrict__ deg,
                              int* __restrict__ pos, int E,
                              const float* __restrict__ W1, unsigned short* __restrict__ w1t,
                              const float* __restrict__ W2, unsigned short* __restrict__ w2t,
                              int EB, int NB1) {
    const int b = blockIdx.x;
    if (b < EB) {
        int i = b * 256 + threadIdx.x;
        if (i < E) pos[i] = atomicAdd(&deg[dst[i]], 1);
    } else if (b < EB + NB1) {
        int t = (b - EB) * 256 + threadIdx.x;       // W1: F_IN rows x HID cols -> w1t[HID][F_IN]
        if (t < F_IN * HID) {
            int n = t / F_IN, k = t - n * F_IN;
            unsigned short v = f2bf(W1[(size_t)k * HID + n]);
#pragma unroll
            for (int r = 0; r < NREP; r++) w1t[(size_t)r * F_IN * HID + t] = v;
        }
    } else {
        int t = (b - EB - NB1) * 256 + threadIdx.x; // W2: HID rows x F_OUT cols -> w2t[F_OUT][HID]
        if (t < HID * F_OUT) {
            int n = t / HID, k = t - n * HID;
            unsigned short v = f2bf(W2[(size_t)k * F_OUT + n]);
#pragma unroll
            for (int r = 0; r < NREP; r++) w2t[(size_t)r * HID * F_OUT + t] = v;
        }
    }
}

// Fused: per-block sum of PADDED deg -> bsums, plus dinv[i] = rsqrt(deg+1) (true deg).
__global__ __launch_bounds__(256) void scan_reduce_dinv(const int* __restrict__ deg,
                                                        int* __restrict__ bsums,
                                                        float* __restrict__ dinv, int N) {
    int i = blockIdx.x * 256 + threadIdx.x;
    int d = (i < N) ? deg[i] : 0;
    if (i < N) dinv[i] = rsqrtf((float)(d + 1));   // +1 = self loop
    int v = (i < N) ? ((d + 15) & ~15) : 0;        // padded degree
#pragma unroll
    for (int ofs = 32; ofs > 0; ofs >>= 1) v += __shfl_down(v, ofs);
    __shared__ int ws[4];
    if ((threadIdx.x & 63) == 0) ws[threadIdx.x >> 6] = v;
    __syncthreads();
    if (threadIdx.x == 0) bsums[blockIdx.x] = ws[0] + ws[1] + ws[2] + ws[3];
}

// Fused: blocks [0,nb): redundant LDS scan of bsums + intra-block scan of PADDED deg
// -> off; blocks [nb, ...): xs = bf16(dinv * x).
__global__ __launch_bounds__(256) void scan_final_scalex(const int* __restrict__ deg,
                                                         const int* __restrict__ bsums,
                                                         int* __restrict__ off, int N, int nb,
                                                         const float* __restrict__ x,
                                                         const float* __restrict__ dinv,
                                                         unsigned short* __restrict__ xs) {
    const int tid = threadIdx.x;
    if ((int)blockIdx.x >= nb) {   // scalex partition
        int i = (blockIdx.x - nb) * 256 + tid;     // one thread per 8 elems
        if (i < N_NODES * F_IN / 8) {
            float dv = dinv[i >> 4];
            float4 v0 = ((const float4*)x)[i * 2];
            float4 v1 = ((const float4*)x)[i * 2 + 1];
            short8 o;
            o[0] = (short)f2bf(v0.x * dv); o[1] = (short)f2bf(v0.y * dv);
            o[2] = (short)f2bf(v0.z * dv); o[3] = (short)f2bf(v0.w * dv);
            o[4] = (short)f2bf(v1.x * dv); o[5] = (short)f2bf(v1.y * dv);
            o[6] = (short)f2bf(v1.z * dv); o[7] = (short)f2bf(v1.w * dv);
            *(short8*)(xs + (size_t)i * 8) = o;
        }
        return;
    }
    __shared__ int bs[256];
    __shared__ int s[256];
    bs[tid] = (tid < nb) ? bsums[tid] : 0;
    const int i = blockIdx.x * 256 + tid;
    int v = (i < N) ? ((deg[i] + 15) & ~15) : 0;   // padded degree
    s[tid] = v;
    __syncthreads();
    for (int ofs = 1; ofs < 256; ofs <<= 1) {
        int tb = (tid >= ofs) ? bs[tid - ofs] : 0;
        int tv = (tid >= ofs) ? s[tid - ofs] : 0;
        __syncthreads();
        bs[tid] += tb;
        s[tid] += tv;
        __syncthreads();
    }
    int bbase = (blockIdx.x == 0) ? 0 : bs[blockIdx.x - 1];
    int excl = (tid == 0) ? 0 : s[tid - 1];
    if (i <= N) off[i] = bbase + excl;
}

// Scatter (byte offsets: src<<8) + pad-fill partition (zero-row offset N<<8).
__global__ void scatter_kernel(const int* __restrict__ src, const int* __restrict__ dst,
                               const int* __restrict__ pos, const int* __restrict__ off,
                               const int* __restrict__ deg, int* __restrict__ csr,
                               int E, int N, int EB) {
    const int b = blockIdx.x;
    if (b < EB) {
        int i = b * 256 + threadIdx.x;
        if (i < E) csr[off[dst[i]] + pos[i]] = src[i] << 8;
    } else {
        int n = (b - EB) * 256 + threadIdx.x;
        if (n < N) {
            const int zoff = N << 8;
            for (int e = off[n] + deg[n]; e < off[n + 1]; e++) csr[e] = zoff;
        }
    }
}

// Wave-per-node aggregation over 128-dim bf16 rows, packed-fp32 accumulate.
// Wave = 4 edge-slots x 16 lanes; 4 nodes per 256-block. CSR padded to x16 with
// zero-row byte offsets -> no predicates/clamps; csr holds byte offsets. Loads as
// i32x4; each dword unpacked (shl / and, exact) + v_pk_add_f32 into f32x2 accs.
// MODE 0: out_bf16[n] = bf16( dinv[n] * (self + sum) )
// MODE 1: out_f32[n]  = dinv[n] * (self + sum) + bias
template <int MODE>
__global__ __launch_bounds__(256) void agg_bf16(const unsigned short* __restrict__ hs,
                                                const int* __restrict__ off,
                                                const int* __restrict__ csr,
                                                const float* __restrict__ dinv,
                                                const float* __restrict__ bias,
                                                void* __restrict__ outp, int N) {
    const int wid = threadIdx.x >> 6;
    const int n = blockIdx.x * 4 + wid;
    if (n >= N) return;
    const int lane = threadIdx.x & 63;
    const int lane16 = lane & 15;
    const int slot = lane >> 4;   // 0..3
    const char* hsl = (const char*)hs + lane16 * 16;   // lane's 16B sub-offset folded in

    f32x2 va2[4], vb2[4], vc2[4], vd2[4];
#pragma unroll
    for (int k = 0; k < 4; k++) {
        va2[k] = (f32x2){0.f, 0.f};
        vb2[k] = (f32x2){0.f, 0.f};
        vc2[k] = (f32x2){0.f, 0.f};
        vd2[k] = (f32x2){0.f, 0.f};
    }

    if (slot == 0) {  // self loop
        i32x4 s = *(const i32x4*)(hsl + ((size_t)n << 8));
#pragma unroll
        for (int k = 0; k < 4; k++) va2[k] = unpk(s[k]);
    }

    const int e0 = off[n];
    const int e1 = off[n + 1];   // padded end (multiple of 16 past e0)
    for (int e = e0 + slot; e < e1; e += 16) {
        int o0 = csr[e];
        int o1 = csr[e + 4];
        int o2 = csr[e + 8];
        int o3 = csr[e + 12];
        i32x4 v0 = *(const i32x4*)(hsl + (unsigned)o0);
        i32x4 v1 = *(const i32x4*)(hsl + (unsigned)o1);
        i32x4 v2 = *(const i32x4*)(hsl + (unsigned)o2);
        i32x4 v3 = *(const i32x4*)(hsl + (unsigned)o3);
#pragma unroll
        for (int k = 0; k < 4; k++) va2[k] += unpk(v0[k]);
#pragma unroll
        for (int k = 0; k < 4; k++) vb2[k] += unpk(v1[k]);
#pragma unroll
        for (int k = 0; k < 4; k++) vc2[k] += unpk(v2[k]);
#pragma unroll
        for (int k = 0; k < 4; k++) vd2[k] += unpk(v3[k]);
    }
#pragma unroll
    for (int k = 0; k < 4; k++) va2[k] += vb2[k] + vc2[k] + vd2[k];

    float va[8];
#pragma unroll
    for (int k = 0; k < 4; k++) { va[2 * k] = va2[k][0]; va[2 * k + 1] = va2[k][1]; }

#pragma unroll
    for (int j = 0; j < 8; j++) va[j] += __shfl_down(va[j], 32);
#pragma unroll
    for (int j = 0; j < 8; j++) va[j] += __shfl_down(va[j], 16);

    if (lane < 16) {
        float dv = dinv[n];
        if (MODE == 0) {
            short8 o;
#pragma unroll
            for (int j = 0; j < 8; j++) o[j] = (short)f2bf(va[j] * dv);
            *(short8*)((unsigned short*)outp + (size_t)n * 128 + lane * 8) = o;
        } else {
            float* op = (float*)outp + (size_t)n * 128 + lane * 8;
            float4 o0, o1;
            o0.x = va[0] * dv + bias[lane * 8 + 0];
            o0.y = va[1] * dv + bias[lane * 8 + 1];
            o0.z = va[2] * dv + bias[lane * 8 + 2];
            o0.w = va[3] * dv + bias[lane * 8 + 3];
            o1.x = va[4] * dv + bias[lane * 8 + 4];
            o1.y = va[5] * dv + bias[lane * 8 + 5];
            o1.z = va[6] * dv + bias[lane * 8 + 6];
            o1.w = va[7] * dv + bias[lane * 8 + 7];
            ((float4*)op)[0] = o0;
            ((float4*)op)[1] = o1;
        }
    }
}

// GEMM1 (straight-line, R15 verbatim): h2[m, 0:256] = relu(Y[m, 0:128] @ W1 + b1).
// 391 blocks x 512 thr (8 waves); block tile = 128 rows; wave = 16 rows x 256 cols.
// W1 in fragment-order LDS (R13-verified mapping, 64 KB, 2 blocks/CU).
__global__ __launch_bounds__(512, 2) void gemm1(const unsigned short* __restrict__ Y,
                                                const unsigned short* __restrict__ w1t,
                                                const float* __restrict__ b1,
                                                unsigned short* __restrict__ h2, int M) {
    __shared__ unsigned short w1l[F_IN * HID];   // 65536 B, fragment-order

    const int tid = threadIdx.x;
    const int wid = tid >> 6;
    const int lane = tid & 63;
    const int an = lane & 15;
    const int q = lane >> 4;
    const int rep = blockIdx.x & (NREP - 1);

    {   // stage W1 replica -> fragment-order LDS (R13-verified)
        const unsigned short* w1r = w1t + (size_t)rep * F_IN * HID;
        for (int i = tid; i < 4096; i += 512) {
            const int cw = i >> 9;
            const int t  = (i >> 8) & 1;
            const int c  = (i >> 6) & 3;
            const int l  = i & 63;
            const int col = cw * 32 + t * 16 + (l & 15);
            const int off = col * F_IN + (l >> 4) * 8 + c * 32;
            *(short8*)(w1l + (size_t)i * 8) = *(const short8*)(w1r + off);
        }
    }
    float bvs[16];
#pragma unroll
    for (int t = 0; t < 16; t++) bvs[t] = b1[t * 16 + an];
    __syncthreads();

    const int m0 = blockIdx.x * 128 + wid * 16;
    int row = m0 + an;
    if (row >= M) row = M - 1;
    short8 a[4];
    {
        const unsigned short* yp = Y + (size_t)row * F_IN + q * 8;
#pragma unroll
        for (int c = 0; c < 4; c++) a[c] = *(const short8*)(yp + c * 32);
    }
    const int mb = m0 + q * 4;
#pragma unroll
    for (int tt = 0; tt < 16; tt++) {
        f32x4 acc = {0.f, 0.f, 0.f, 0.f};
#pragma unroll
        for (int c = 0; c < 4; c++) {
            const short8 b = *(const short8*)(w1l +
                              ((size_t)(((tt >> 1) * 8 + (tt & 1) * 4 + c) * 64 + lane)) * 8);
            acc = __builtin_amdgcn_mfma_f32_16x16x32_bf16(a[c], b, acc, 0, 0, 0);
        }
        const int col = tt * 16 + an;
#pragma unroll
        for (int rr = 0; rr < 4; rr++) {
            const int m = mb + rr;
            if (m < M) h2[(size_t)m * HID + col] = f2bf(fmaxf(acc[rr] + bvs[tt], 0.f));
        }
    }
}

// GEMM2 (straight-line, R15 verbatim): hs2[m, 0:128] = dinv[m] * (h2[m, 0:256] @ W2).
__global__ __launch_bounds__(512, 2) void gemm2(const unsigned short* __restrict__ h2,
                                                const unsigned short* __restrict__ w2t,
                                                const float* __restrict__ dinv,
                                                unsigned short* __restrict__ hs2, int M) {
    __shared__ unsigned short w2l[HID * F_OUT];   // 65536 B, fragment-order

    const int tid = threadIdx.x;
    const int wid = tid >> 6;
    const int lane = tid & 63;
    const int an = lane & 15;
    const int q = lane >> 4;
    const int rep = blockIdx.x & (NREP - 1);

    {   // stage W2 replica -> fragment-order LDS (R13-verified)
        const unsigned short* w2r = w2t + (size_t)rep * HID * F_OUT;
        for (int i = tid; i < 4096; i += 512) {
            const int cw = i >> 9;
            const int c  = (i >> 6) & 7;
            const int l  = i & 63;
            const int colB = cw * 16 + (l & 15);
            const int off = colB * HID + (l >> 4) * 8 + c * 32;
            *(short8*)(w2l + (size_t)i * 8) = *(const short8*)(w2r + off);
        }
    }
    __syncthreads();

    const int m0 = blockIdx.x * 128 + wid * 16;
    int row = m0 + an;
    if (row >= M) row = M - 1;
    short8 a[8];
    {
        const unsigned short* hp = h2 + (size_t)row * HID + q * 8;
#pragma unroll
        for (int c = 0; c < 8; c++) a[c] = *(const short8*)(hp + c * 32);
    }
    const int mb = m0 + q * 4;
    float dv[4];
#pragma unroll
    for (int rr = 0; rr < 4; rr++) dv[rr] = (mb + rr < M) ? dinv[mb + rr] : 0.f;
#pragma unroll
    for (int tt = 0; tt < 8; tt++) {
        f32x4 acc = {0.f, 0.f, 0.f, 0.f};
#pragma unroll
        for (int c = 0; c < 8; c++) {
            const short8 b = *(const short8*)(w2l + ((size_t)((tt * 8 + c) * 64 + lane)) * 8);
            acc = __builtin_amdgcn_mfma_f32_16x16x32_bf16(a[c], b, acc, 0, 0, 0);
        }
        const int col = tt * 16 + an;
#pragma unroll
        for (int rr = 0; rr < 4; rr++) {
            const int m = mb + rr;
            if (m < M) hs2[(size_t)m * F_OUT + col] = f2bf(acc[rr] * dv[rr]);
        }
    }
}

extern "C" void kernel_launch(void* const* d_in, const int* in_sizes, int n_in,
                              void* d_out, int out_size, void* d_ws, size_t ws_size,
                              hipStream_t stream) {
    const float* x  = (const float*)d_in[0];
    const int*   ei = (const int*)d_in[1];   // [2,E] int32
    const float* W1 = (const float*)d_in[2];
    const float* b1 = (const float*)d_in[3];
    const float* W2 = (const float*)d_in[4];
    const float* b2 = (const float*)d_in[5];

    const int N = N_NODES;
    const int E = N_EDGES;
    const int* srcp = ei;
    const int* dstp = ei + E;

    char* base = (char*)d_ws;
    size_t o = 0;
    auto alloc = [&](size_t bytes) {
        void* p = base + o;
        o = (o + bytes + 255) & ~(size_t)255;
        return p;
    };
    int*            deg  = (int*)alloc((size_t)N * 4);
    int*            offs = (int*)alloc((size_t)(N + 1) * 4);
    float*          dinv = (float*)alloc((size_t)N * 4);
    int*            bsum = (int*)alloc(256 * 4);
    int*            pos  = (int*)alloc((size_t)E * 4);
    int*            csr  = (int*)alloc(((size_t)E + 16 * (N + 1)) * 4);   // padded CSR
    unsigned short* xs   = (unsigned short*)alloc((size_t)(N + 1) * F_IN * 2); // +zero row N
    unsigned short* Y    = (unsigned short*)alloc((size_t)N * F_IN * 2);  // A_hat@X, bf16
    unsigned short* h2   = (unsigned short*)alloc((size_t)N * HID * 2);   // relu(Y@W1+b1), bf16
    unsigned short* w1t  = (unsigned short*)alloc((size_t)NREP * F_IN * HID * 2);
    unsigned short* w2t  = (unsigned short*)alloc((size_t)NREP * HID * F_OUT * 2);
    unsigned short* hs2  = xs;  // xs dead after agg1 (row N stays zero for agg2)

    hipMemsetAsync(deg, 0, (size_t)N * 4, stream);
    hipMemsetAsync(xs + (size_t)N * F_IN, 0, F_IN * 2, stream);   // zero row N

    const int NB  = (N + 256) / 256;           // 196, covers i==N in scan_final
    const int NBX = (N * F_IN / 8 + 255) / 256;
    const int NBn = (N + 255) / 256;
    const int EB  = (E + 255) / 256;
    const int NB1 = (F_IN * HID + 255) / 256;
    const int NB2 = (HID * F_OUT + 255) / 256;
    const int GB  = (N + 127) / 128;           // 391 GEMM blocks

    deg_wt_kernel<<<EB + NB1 + NB2, 256, 0, stream>>>(dstp, deg, pos, E, W1, w1t, W2, w2t, EB, NB1);
    scan_reduce_dinv<<<NB, 256, 0, stream>>>(deg, bsum, dinv, N);
    scan_final_scalex<<<NB + NBX, 256, 0, stream>>>(deg, bsum, offs, N, NB, x, dinv, xs);
    scatter_kernel<<<EB + NBn, 256, 0, stream>>>(srcp, dstp, pos, offs, deg, csr, E, N, EB);

    // layer 1 agg: Y = A_hat@X (bf16 gather, padded predicate-free packed-fp32 batches)
    agg_bf16<0><<<(N + 3) / 4, 256, 0, stream>>>(xs, offs, csr, dinv, nullptr, Y, N);
    // split GEMMs (R15 verbatim): h2 = relu(Y@W1+b1);  hs2 = dinv*(h2@W2)
    gemm1<<<GB, 512, 0, stream>>>(Y, w1t, b1, h2, N);
    gemm2<<<GB, 512, 0, stream>>>(h2, w2t, dinv, hs2, N);
    // layer 2 agg: out = dinv*(hs2[self]+gather) + b2
    agg_bf16<1><<<(N + 3) / 4, 256, 0, stream>>>(hs2, offs, csr, dinv, b2, d_out, N);
}